// Round 11
// baseline (482.086 us; speedup 1.0000x reference)
//
#include <hip/hip_runtime.h>
#include <cstddef>

#define NFRM 247
#define NBIN 128
#define NC   32
#define NWIN 58
#define NMAT (8 * NWIN * 6)   // 2784

// ---------------- K1: STFT (16x16 split DFT, bins 1..128) ----------------
// spec layout: (b, frame, f-1, c) float2
__global__ __launch_bounds__(128) void k_stft(const float* __restrict__ x,
                                              float2* __restrict__ spec) {
  const int gid = blockIdx.x;          // (b*32+c)*247 + fr
  const int fr  = gid % NFRM;
  const int bc  = gid / NFRM;
  const int tid = threadIdx.x;

  __shared__ float  xw[256];
  __shared__ float2 tw[256];
  __shared__ float2 Y[256];            // [f0][t0]

  const float* xp = x + ((size_t)bc * 16000 + (size_t)fr * 64);

  #pragma unroll
  for (int k = 0; k < 2; ++k) {
    const int t = tid + k * 128;
    const float wv = 0.5f - 0.5f * __cosf((float)t * 0.024639942f); // 2pi/255 (np.hanning)
    xw[t] = xp[t] * wv * 0.10226200f;                               // / ||w||  (||w||^2 = 95.625)
    float sv, cv;
    __sincosf((float)t * 0.024543693f, &sv, &cv);                   // 2pi/256
    tw[t] = make_float2(cv, -sv);                                   // e^{-2pi i m/256}
  }
  __syncthreads();

  // stage A: Y[f0][t0] = sum_t1 xw[16*t1+t0] * e^{-2pi i f0 t1/16}
  #pragma unroll
  for (int k = 0; k < 2; ++k) {
    const int e = tid + k * 128;
    const int f0 = e >> 4, t0 = e & 15;
    const int step = (f0 << 4) & 255;
    float re = 0.f, im = 0.f;
    int m = 0;
    #pragma unroll
    for (int t1 = 0; t1 < 16; ++t1) {
      const float v = xw[(t1 << 4) + t0];
      const float2 w = tw[m];
      re = fmaf(v, w.x, re);
      im = fmaf(v, w.y, im);
      m = (m + step) & 255;
    }
    Y[e] = make_float2(re, im);
  }
  __syncthreads();

  // stage B: spec[f] = sum_t0 Y[f&15][t0] * e^{-2pi i f t0/256},  f = tid+1
  const int f = tid + 1;               // 1..128
  const int f0 = f & 15;
  float re = 0.f, im = 0.f;
  int m = 0;
  #pragma unroll
  for (int t0 = 0; t0 < 16; ++t0) {
    const float2 yv = Y[(f0 << 4) + t0];
    const float2 w = tw[m];
    re += yv.x * w.x - yv.y * w.y;
    im += yv.x * w.y + yv.y * w.x;
    m = (m + f) & 255;
  }
  const int b = bc >> 5, c = bc & 31;
  spec[(((size_t)b * NFRM + fr) * NBIN + (f - 1)) * NC + c] = make_float2(re, im);
}

// ---------------- K2: CSD + |.|^2 + band average (f-split, partial sums) ----------------
// R9-proven: barrier-free wave-private 2-deep ring staging; one barrier before the
// cross-wave reduction (red[] overlays the ring).
// part layout: (p, b*58+t, k, i, j) float
__global__ __launch_bounds__(256) void k_csd(const float2* __restrict__ spec,
                                             float* __restrict__ part, int P) {
  const int bt  = blockIdx.x;          // b*58 + t
  const int p   = blockIdx.y;
  const int b   = bt / NWIN, t = bt % NWIN;
  const int tid = threadIdx.x;
  const int wv  = tid >> 6;            // wave 0..3
  const int lane = tid & 63;
  const int i0 = (lane >> 3) * 4;
  const int j0 = (lane & 7) * 4;

  __shared__ __align__(16) char smemraw[32768];          // ring (32KB) / red (24KB) overlay
  float2 (*rng)[2][512] = reinterpret_cast<float2 (*)[2][512]>(smemraw);
  float* red = reinterpret_cast<float*>(smemraw);

  float bacc[6][16];
  #pragma unroll
  for (int k = 0; k < 6; ++k)
    #pragma unroll
    for (int e = 0; e < 16; ++e) bacc[k][e] = 0.f;

  const float2* sb = spec + (size_t)b * NFRM * NBIN * NC;
  const int itn = 32 / P;

  for (int itl = 0; itl < itn; ++itl) {
    const int f = 1 + wv + 4 * (itn * p + itl);     // wave-uniform bin
    float2* Xs = rng[wv][itl & 1];                  // wave-private staging buffer
    // stage X[s][c] = spec[b][t*4+s][f-1][c]
    #pragma unroll
    for (int r = 0; r < 8; ++r) {
      const int e = lane + r * 64;
      const int s = e >> 5, cc = e & 31;
      Xs[e] = sb[((size_t)(t * 4 + s) * NBIN + (f - 1)) * NC + cc];
    }
    // no __syncthreads: buffer is wave-private; per-wave DS ops are in-order

    float accRe[16], accIm[16];
    #pragma unroll
    for (int e = 0; e < 16; ++e) { accRe[e] = 0.f; accIm[e] = 0.f; }

    #pragma unroll
    for (int s = 0; s < 16; ++s) {
      float2 xi[4], xj[4];
      #pragma unroll
      for (int a = 0; a < 4; ++a) {
        xi[a] = Xs[s * 32 + i0 + a];
        xj[a] = Xs[s * 32 + j0 + a];
      }
      #pragma unroll
      for (int a = 0; a < 4; ++a)
        #pragma unroll
        for (int d = 0; d < 4; ++d) {
          const int e = a * 4 + d;
          // M_ij += x_i * conj(x_j)
          accRe[e] = fmaf(xi[a].x, xj[d].x, fmaf(xi[a].y, xj[d].y, accRe[e]));
          accIm[e] = fmaf(xi[a].y, xj[d].x, fmaf(-xi[a].x, xj[d].y, accIm[e]));
        }
    }

    #define ACCB(K) { _Pragma("unroll") \
      for (int e = 0; e < 16; ++e) { float rr = accRe[e], ii = accIm[e]; \
        bacc[K][e] = fmaf(rr, rr, fmaf(ii, ii, bacc[K][e])); } }
    if      (f <= 3)  ACCB(0)
    else if (f <= 6)  ACCB(1)
    else if (f <= 12) ACCB(2)
    else if (f <= 25) ACCB(3)
    else if (f <= 51) ACCB(4)
    else              ACCB(5)
    #undef ACCB
  }

  __syncthreads();   // all waves done with ring before red[] overlay is written

  // cross-wave reduction in LDS
  for (int w2 = 0; w2 < 4; ++w2) {
    if (wv == w2) {
      #pragma unroll
      for (int k = 0; k < 6; ++k)
        #pragma unroll
        for (int a = 0; a < 4; ++a)
          #pragma unroll
          for (int d = 0; d < 4; ++d) {
            const int idx = k * 1024 + (i0 + a) * 32 + (j0 + d);
            const float v = bacc[k][a * 4 + d];
            if (w2 == 0) red[idx] = v; else red[idx] += v;
          }
    }
    __syncthreads();
  }

  // scale: |M/16|^2 / band_count  = raw/(256*cnt),  cnt = {3,3,6,13,26,77}
  float* op = part + ((size_t)p * (8 * NWIN) + bt) * 6144;
  for (int u = tid; u < 6144; u += 256) {
    const int k = u >> 10;
    float scl;
    if      (k <= 1) scl = 1.f / 768.f;
    else if (k == 2) scl = 1.f / 1536.f;
    else if (k == 3) scl = 1.f / 3328.f;
    else if (k == 4) scl = 1.f / 6656.f;
    else             scl = 1.f / 19712.f;
    op[u] = red[u] * scl;
  }
}

// ---------------- K3: one-sided Jacobi eig + matrix log ----------------
// ONE matrix per 64-lane wave: lane = col + 32*half; lane holds rows [16h,16h+16)
// of column col. Half-combine via __shfl_xor(.,32) — R9-proven (permlane32_swap
// orientation was wrong on HW; reverted).
__global__ __launch_bounds__(64) void k_eig(const float* __restrict__ part,
                                            float* __restrict__ eigTmp, int P) {
  const int blk  = blockIdx.x;         // matrix id = (b*58+t)*6 + k
  const int lane = threadIdx.x;
  const int h    = lane >> 5;          // half: rows [16h, 16h+16)
  const int c    = lane & 31;          // column

  __shared__ float sA[32][36];         // phase 1: A row-major; phase 2: G TRANSPOSED [col][row]
  __shared__ float sSc[32];

  // load matrix (sum P partial band slices)
  for (int u = lane; u < 1024; u += 64) {
    const size_t base = (size_t)blk * 1024 + u;
    float s = 0.f;
    for (int p = 0; p < P; ++p) s += part[(size_t)p * ((size_t)NMAT * 1024) + base];
    sA[u >> 5][u & 31] = s;
  }
  __syncthreads();

  float g[16];
  #pragma unroll
  for (int i = 0; i < 16; ++i) g[i] = sA[16 * h + i][c];

  // full column norm, canonical lo+hi order (bitwise-identical on both half-lanes)
  float n;
  {
    float p0 = 0.f, p1 = 0.f, p2 = 0.f, p3 = 0.f;
    #pragma unroll
    for (int e = 0; e < 16; e += 4) {
      p0 = fmaf(g[e + 0], g[e + 0], p0);
      p1 = fmaf(g[e + 1], g[e + 1], p1);
      p2 = fmaf(g[e + 2], g[e + 2], p2);
      p3 = fmaf(g[e + 3], g[e + 3], p3);
    }
    const float pp = (p0 + p1) + (p2 + p3);
    const float op = __shfl_xor(pp, 32);
    n = h ? (op + pp) : (pp + op);
  }

  // Stop threshold: |cos(angle)| > sqrt(EPS2). Output-error bound for residual
  // coupling bpq <= eps*sqrt(lp*lq): err <= 0.74*eps (geometric-mean self-limiting),
  // so EPS2=1e-7 (eps=3.2e-4) keeps output error ~2e-4 << 4.8e-2 threshold.
  const float EPS2 = 1e-7f;
  #pragma unroll 1
  for (int sweep = 0; sweep < 10; ++sweep) {
    int anybad = 0;
    #pragma unroll 1
    for (int m = 1; m < 32; ++m) {    // XOR pairing; m<32 keeps the half bit
      const int pidx = (lane ^ m) << 2;
      float tmp[16];
      #pragma unroll
      for (int e = 0; e < 16; ++e)
        tmp[e] = __int_as_float(__builtin_amdgcn_ds_bpermute(pidx, __float_as_int(g[e])));
      const float np = __int_as_float(__builtin_amdgcn_ds_bpermute(pidx, __float_as_int(n)));

      float d0 = 0.f, d1 = 0.f, d2 = 0.f, d3 = 0.f;
      #pragma unroll
      for (int e = 0; e < 16; e += 4) {
        d0 = fmaf(g[e + 0], tmp[e + 0], d0);
        d1 = fmaf(g[e + 1], tmp[e + 1], d1);
        d2 = fmaf(g[e + 2], tmp[e + 2], d2);
        d3 = fmaf(g[e + 3], tmp[e + 3], d3);
      }
      const float pp = (d0 + d1) + (d2 + d3);
      const float op = __shfl_xor(pp, 32);
      const float bpq = h ? (op + pp) : (pp + op);   // identical on all 4 pair lanes

      const int bad = (bpq * bpq > EPS2 * n * np);
      anybad |= bad;
      if (bad) {
        // tau on partner lane is exact negation -> tf exact negation -> consistent pair rotation
        const float tau = (np - n) * 0.5f * __builtin_amdgcn_rcpf(bpq);
        float tf = __builtin_amdgcn_rcpf(fabsf(tau) + __builtin_amdgcn_sqrtf(fmaf(tau, tau, 1.f)));
        if (tau < 0.f) tf = -tf;
        const float cr = __builtin_amdgcn_rsqf(fmaf(tf, tf, 1.f));
        const float sg = -tf * cr;
        n = fmaf(-tf, bpq, n);
        #pragma unroll
        for (int e = 0; e < 16; ++e) g[e] = fmaf(sg, tmp[e], cr * g[e]);
      }
    }
    if (!__any(anybad)) break;
  }

  // exact norm; lambda = sqrt(nx); floor 100*eps folded: 0.5*log(max(nx, floor^2))
  float nx;
  {
    float p0 = 0.f, p1 = 0.f, p2 = 0.f, p3 = 0.f;
    #pragma unroll
    for (int e = 0; e < 16; e += 4) {
      p0 = fmaf(g[e + 0], g[e + 0], p0);
      p1 = fmaf(g[e + 1], g[e + 1], p1);
      p2 = fmaf(g[e + 2], g[e + 2], p2);
      p3 = fmaf(g[e + 3], g[e + 3], p3);
    }
    const float pp = (p0 + p1) + (p2 + p3);
    const float op = __shfl_xor(pp, 32);
    nx = h ? (op + pp) : (pp + op);
  }
  const float lv = 0.5f * __logf(fmaxf(nx, 1.4210855e-10f));
  const float sc = (nx > 1e-32f) ? (lv * __builtin_amdgcn_rcpf(nx)) : 0.f;

  __syncthreads();                     // done with sA as A; reuse for G^T
  // store G TRANSPOSED: sA[col][row] = G[row][col]  (so G[j][e] = sA[e][j])
  #pragma unroll
  for (int i = 0; i < 16; ++i) sA[c][16 * h + i] = g[i];
  if (h == 0) sSc[c] = sc;
  __syncthreads();

  // out[r][j] = sum_e sc_e * G[r][e] * G[j][e];  lane does row r=c, cols [16h,16h+16)
  float a[32];
  #pragma unroll
  for (int e = 0; e < 32; ++e) a[e] = sSc[e] * sA[e][c];   // sc_e * G[c][e]

  float* ob = eigTmp + ((size_t)blk * 1024 + c * 32 + 16 * h);
  #pragma unroll
  for (int q = 0; q < 4; ++q) {
    float4 acc = make_float4(0.f, 0.f, 0.f, 0.f);
    #pragma unroll
    for (int e = 0; e < 32; ++e) {
      const float4 gv = *(const float4*)&sA[e][16 * h + 4 * q];   // G[j..j+3][e], broadcast
      acc.x = fmaf(a[e], gv.x, acc.x);
      acc.y = fmaf(a[e], gv.y, acc.y);
      acc.z = fmaf(a[e], gv.z, acc.z);
      acc.w = fmaf(a[e], gv.w, acc.w);
    }
    *(float4*)(ob + 4 * q) = acc;
  }
}

// ---------------- K4: transpose (b,t,k,ij) -> out (b,k,ij,t) ----------------
__global__ __launch_bounds__(256) void k_tr(const float* __restrict__ eigTmp,
                                            float* __restrict__ out) {
  const int bk    = blockIdx.x >> 3;   // b*6 + k
  const int chunk = blockIdx.x & 7;
  const int b = bk / 6, k = bk % 6;
  const int ij0 = chunk * 128;
  const int tid = threadIdx.x;

  __shared__ float tile[128 * 59];

  for (int u = tid; u < 128 * NWIN; u += 256) {
    const int t = u >> 7, ijl = u & 127;
    tile[ijl * 59 + t] = eigTmp[((size_t)(b * NWIN + t) * 6 + k) * 1024 + ij0 + ijl];
  }
  __syncthreads();

  float* ob = out + ((size_t)bk * 1024 + ij0) * NWIN;
  for (int u = tid; u < 128 * NWIN; u += 256) {
    ob[u] = tile[(u / NWIN) * 59 + (u % NWIN)];
  }
}

extern "C" void kernel_launch(void* const* d_in, const int* in_sizes, int n_in,
                              void* d_out, int out_size, void* d_ws, size_t ws_size,
                              hipStream_t stream) {
  const float* x = (const float*)d_in[0];
  float* outp = (float*)d_out;

  const size_t SPEC_B = (size_t)8 * NFRM * NBIN * NC * sizeof(float2);   // 64.75 MB
  const size_t BAND_B = (size_t)NMAT * 1024 * sizeof(float);             // 11.4 MB

  float2* spec   = (float2*)d_ws;
  float*  part   = (float*)((char*)d_ws + SPEC_B);
  float*  eigTmp = (float*)d_ws;       // reuses spec region (dead after k_csd)

  int P = 1;
  if      (ws_size >= SPEC_B + 4 * BAND_B) P = 4;
  else if (ws_size >= SPEC_B + 2 * BAND_B) P = 2;

  k_stft<<<dim3(8 * 32 * NFRM), dim3(128), 0, stream>>>(x, spec);
  k_csd <<<dim3(8 * NWIN, P),   dim3(256), 0, stream>>>(spec, part, P);
  k_eig <<<dim3(NMAT),          dim3(64),  0, stream>>>(part, eigTmp, P);
  k_tr  <<<dim3(48 * 8),        dim3(256), 0, stream>>>(eigTmp, outp);
}

// Round 12
// 452.731 us; speedup vs baseline: 1.0648x; 1.0648x over previous
//
#include <hip/hip_runtime.h>
#include <cstddef>

#define NFRM 247
#define NBIN 128
#define NC   32
#define NWIN 58
#define NMAT (8 * NWIN * 6)   // 2784

// ---------------- K1: STFT (16x16 split DFT, bins 1..128) ----------------
// spec layout: (b, frame, f-1, c) float2
__global__ __launch_bounds__(128) void k_stft(const float* __restrict__ x,
                                              float2* __restrict__ spec) {
  const int gid = blockIdx.x;          // (b*32+c)*247 + fr
  const int fr  = gid % NFRM;
  const int bc  = gid / NFRM;
  const int tid = threadIdx.x;

  __shared__ float  xw[256];
  __shared__ float2 tw[256];
  __shared__ float2 Y[256];            // [f0][t0]

  const float* xp = x + ((size_t)bc * 16000 + (size_t)fr * 64);

  #pragma unroll
  for (int k = 0; k < 2; ++k) {
    const int t = tid + k * 128;
    const float wv = 0.5f - 0.5f * __cosf((float)t * 0.024639942f); // 2pi/255 (np.hanning)
    xw[t] = xp[t] * wv * 0.10226200f;                               // / ||w||  (||w||^2 = 95.625)
    float sv, cv;
    __sincosf((float)t * 0.024543693f, &sv, &cv);                   // 2pi/256
    tw[t] = make_float2(cv, -sv);                                   // e^{-2pi i m/256}
  }
  __syncthreads();

  // stage A: Y[f0][t0] = sum_t1 xw[16*t1+t0] * e^{-2pi i f0 t1/16}
  #pragma unroll
  for (int k = 0; k < 2; ++k) {
    const int e = tid + k * 128;
    const int f0 = e >> 4, t0 = e & 15;
    const int step = (f0 << 4) & 255;
    float re = 0.f, im = 0.f;
    int m = 0;
    #pragma unroll
    for (int t1 = 0; t1 < 16; ++t1) {
      const float v = xw[(t1 << 4) + t0];
      const float2 w = tw[m];
      re = fmaf(v, w.x, re);
      im = fmaf(v, w.y, im);
      m = (m + step) & 255;
    }
    Y[e] = make_float2(re, im);
  }
  __syncthreads();

  // stage B: spec[f] = sum_t0 Y[f&15][t0] * e^{-2pi i f t0/256},  f = tid+1
  const int f = tid + 1;               // 1..128
  const int f0 = f & 15;
  float re = 0.f, im = 0.f;
  int m = 0;
  #pragma unroll
  for (int t0 = 0; t0 < 16; ++t0) {
    const float2 yv = Y[(f0 << 4) + t0];
    const float2 w = tw[m];
    re += yv.x * w.x - yv.y * w.y;
    im += yv.x * w.y + yv.y * w.x;
    m = (m + f) & 255;
  }
  const int b = bc >> 5, c = bc & 31;
  spec[(((size_t)b * NFRM + fr) * NBIN + (f - 1)) * NC + c] = make_float2(re, im);
}

// ---------------- K2: CSD + |.|^2 + band average (f-split, partial sums) ----------------
// R9-proven barrier-free wave-private ring staging + R12 software pipeline:
// iter k+1's global loads are issued into registers BEFORE consuming iter k from LDS
// (HBM latency hides under the 256-FMA consume), ds_write lands after the consume.
// part layout: (p, b*58+t, k, i, j) float
__global__ __launch_bounds__(256) void k_csd(const float2* __restrict__ spec,
                                             float* __restrict__ part, int P) {
  const int bt  = blockIdx.x;          // b*58 + t
  const int p   = blockIdx.y;
  const int b   = bt / NWIN, t = bt % NWIN;
  const int tid = threadIdx.x;
  const int wv  = tid >> 6;            // wave 0..3
  const int lane = tid & 63;
  const int i0 = (lane >> 3) * 4;
  const int j0 = (lane & 7) * 4;

  __shared__ __align__(16) char smemraw[32768];          // ring (32KB) / red (24KB) overlay
  float2 (*rng)[2][512] = reinterpret_cast<float2 (*)[2][512]>(smemraw);
  float* red = reinterpret_cast<float*>(smemraw);

  float bacc[6][16];
  #pragma unroll
  for (int k = 0; k < 6; ++k)
    #pragma unroll
    for (int e = 0; e < 16; ++e) bacc[k][e] = 0.f;

  const float2* sb = spec + (size_t)b * NFRM * NBIN * NC;
  const int itn = 32 / P;

  // global address for staging element r of bin-iteration itl (identical math to R9):
  // sb[(t*4 + s)*NBIN*NC + (f-1)*NC + cc],  e = lane + r*64, s = e>>5, cc = e&31
  #define STG_LOAD(itl, dst)                                                     \
    {                                                                            \
      const int f_ = 1 + wv + 4 * (itn * p + (itl));                             \
      const float2* fp_ = sb + (size_t)(f_ - 1) * NC;                            \
      _Pragma("unroll")                                                          \
      for (int r = 0; r < 8; ++r) {                                              \
        const int e_ = lane + r * 64;                                            \
        dst[r] = fp_[(size_t)(t * 4 + (e_ >> 5)) * (NBIN * NC) + (e_ & 31)];     \
      }                                                                          \
    }

  // prologue: stage itl=0
  {
    float2 stg[8];
    STG_LOAD(0, stg)
    float2* Xs = rng[wv][0];
    #pragma unroll
    for (int r = 0; r < 8; ++r) Xs[lane + r * 64] = stg[r];
  }

  for (int itl = 0; itl < itn; ++itl) {
    // prefetch next iteration into registers (in flight during consume)
    float2 stg2[8];
    if (itl + 1 < itn) STG_LOAD(itl + 1, stg2)

    const int f = 1 + wv + 4 * (itn * p + itl);     // wave-uniform bin
    const float2* Xs = rng[wv][itl & 1];

    float accRe[16], accIm[16];
    #pragma unroll
    for (int e = 0; e < 16; ++e) { accRe[e] = 0.f; accIm[e] = 0.f; }

    #pragma unroll
    for (int s = 0; s < 16; ++s) {
      float2 xi[4], xj[4];
      #pragma unroll
      for (int a = 0; a < 4; ++a) {
        xi[a] = Xs[s * 32 + i0 + a];
        xj[a] = Xs[s * 32 + j0 + a];
      }
      #pragma unroll
      for (int a = 0; a < 4; ++a)
        #pragma unroll
        for (int d = 0; d < 4; ++d) {
          const int e = a * 4 + d;
          // M_ij += x_i * conj(x_j)
          accRe[e] = fmaf(xi[a].x, xj[d].x, fmaf(xi[a].y, xj[d].y, accRe[e]));
          accIm[e] = fmaf(xi[a].y, xj[d].x, fmaf(-xi[a].x, xj[d].y, accIm[e]));
        }
    }

    #define ACCB(K) { _Pragma("unroll") \
      for (int e = 0; e < 16; ++e) { float rr = accRe[e], ii = accIm[e]; \
        bacc[K][e] = fmaf(rr, rr, fmaf(ii, ii, bacc[K][e])); } }
    if      (f <= 3)  ACCB(0)
    else if (f <= 6)  ACCB(1)
    else if (f <= 12) ACCB(2)
    else if (f <= 25) ACCB(3)
    else if (f <= 51) ACCB(4)
    else              ACCB(5)
    #undef ACCB

    // write next iteration's staged data (wave-private, in-order DS => no barrier)
    if (itl + 1 < itn) {
      float2* Xn = rng[wv][(itl + 1) & 1];
      #pragma unroll
      for (int r = 0; r < 8; ++r) Xn[lane + r * 64] = stg2[r];
    }
  }
  #undef STG_LOAD

  __syncthreads();   // all waves done with ring before red[] overlay is written

  // cross-wave reduction in LDS
  for (int w2 = 0; w2 < 4; ++w2) {
    if (wv == w2) {
      #pragma unroll
      for (int k = 0; k < 6; ++k)
        #pragma unroll
        for (int a = 0; a < 4; ++a)
          #pragma unroll
          for (int d = 0; d < 4; ++d) {
            const int idx = k * 1024 + (i0 + a) * 32 + (j0 + d);
            const float v = bacc[k][a * 4 + d];
            if (w2 == 0) red[idx] = v; else red[idx] += v;
          }
    }
    __syncthreads();
  }

  // scale: |M/16|^2 / band_count  = raw/(256*cnt),  cnt = {3,3,6,13,26,77}
  float* op = part + ((size_t)p * (8 * NWIN) + bt) * 6144;
  for (int u = tid; u < 6144; u += 256) {
    const int k = u >> 10;
    float scl;
    if      (k <= 1) scl = 1.f / 768.f;
    else if (k == 2) scl = 1.f / 1536.f;
    else if (k == 3) scl = 1.f / 3328.f;
    else if (k == 4) scl = 1.f / 6656.f;
    else             scl = 1.f / 19712.f;
    op[u] = red[u] * scl;
  }
}

// ---------------- K3: one-sided Jacobi eig + matrix log ----------------
// ONE matrix per 64-lane wave: lane = col + 32*half; lane holds rows [16h,16h+16)
// of column col. Half-combine via __shfl_xor(.,32) (R9-proven).
__global__ __launch_bounds__(64) void k_eig(const float* __restrict__ part,
                                            float* __restrict__ eigTmp, int P) {
  const int blk  = blockIdx.x;         // matrix id = (b*58+t)*6 + k
  const int lane = threadIdx.x;
  const int h    = lane >> 5;          // half: rows [16h, 16h+16)
  const int c    = lane & 31;          // column

  __shared__ float sA[32][36];         // phase 1: A row-major; phase 2: G TRANSPOSED [col][row]
  __shared__ float sSc[32];

  // load matrix (sum P partial band slices)
  for (int u = lane; u < 1024; u += 64) {
    const size_t base = (size_t)blk * 1024 + u;
    float s = 0.f;
    for (int p = 0; p < P; ++p) s += part[(size_t)p * ((size_t)NMAT * 1024) + base];
    sA[u >> 5][u & 31] = s;
  }
  __syncthreads();

  float g[16];
  #pragma unroll
  for (int i = 0; i < 16; ++i) g[i] = sA[16 * h + i][c];

  // full column norm, canonical lo+hi order (bitwise-identical on both half-lanes)
  float n;
  {
    float p0 = 0.f, p1 = 0.f, p2 = 0.f, p3 = 0.f;
    #pragma unroll
    for (int e = 0; e < 16; e += 4) {
      p0 = fmaf(g[e + 0], g[e + 0], p0);
      p1 = fmaf(g[e + 1], g[e + 1], p1);
      p2 = fmaf(g[e + 2], g[e + 2], p2);
      p3 = fmaf(g[e + 3], g[e + 3], p3);
    }
    const float pp = (p0 + p1) + (p2 + p3);
    const float op = __shfl_xor(pp, 32);
    n = h ? (op + pp) : (pp + op);
  }

  // Stop threshold: residual coupling bpq <= eps*sqrt(lp*lq) => output error <= 0.74*eps;
  // EPS2=1e-7 (eps=3.2e-4) keeps output error ~2e-4 << 4.8e-2 threshold. [R11-validated]
  const float EPS2 = 1e-7f;
  #pragma unroll 1
  for (int sweep = 0; sweep < 10; ++sweep) {
    int anybad = 0;
    #pragma unroll 1
    for (int m = 1; m < 32; ++m) {    // XOR pairing; m<32 keeps the half bit
      const int pidx = (lane ^ m) << 2;
      float tmp[16];
      #pragma unroll
      for (int e = 0; e < 16; ++e)
        tmp[e] = __int_as_float(__builtin_amdgcn_ds_bpermute(pidx, __float_as_int(g[e])));
      const float np = __int_as_float(__builtin_amdgcn_ds_bpermute(pidx, __float_as_int(n)));

      float d0 = 0.f, d1 = 0.f, d2 = 0.f, d3 = 0.f;
      #pragma unroll
      for (int e = 0; e < 16; e += 4) {
        d0 = fmaf(g[e + 0], tmp[e + 0], d0);
        d1 = fmaf(g[e + 1], tmp[e + 1], d1);
        d2 = fmaf(g[e + 2], tmp[e + 2], d2);
        d3 = fmaf(g[e + 3], tmp[e + 3], d3);
      }
      const float pp = (d0 + d1) + (d2 + d3);
      const float op = __shfl_xor(pp, 32);
      const float bpq = h ? (op + pp) : (pp + op);   // identical on all 4 pair lanes

      const int bad = (bpq * bpq > EPS2 * n * np);
      anybad |= bad;
      if (bad) {
        // tau on partner lane is exact negation -> tf exact negation -> consistent pair rotation
        const float tau = (np - n) * 0.5f * __builtin_amdgcn_rcpf(bpq);
        float tf = __builtin_amdgcn_rcpf(fabsf(tau) + __builtin_amdgcn_sqrtf(fmaf(tau, tau, 1.f)));
        if (tau < 0.f) tf = -tf;
        const float cr = __builtin_amdgcn_rsqf(fmaf(tf, tf, 1.f));
        const float sg = -tf * cr;
        n = fmaf(-tf, bpq, n);
        #pragma unroll
        for (int e = 0; e < 16; ++e) g[e] = fmaf(sg, tmp[e], cr * g[e]);
      }
    }
    if (!__any(anybad)) break;
  }

  // exact norm; lambda = sqrt(nx); floor 100*eps folded: 0.5*log(max(nx, floor^2))
  float nx;
  {
    float p0 = 0.f, p1 = 0.f, p2 = 0.f, p3 = 0.f;
    #pragma unroll
    for (int e = 0; e < 16; e += 4) {
      p0 = fmaf(g[e + 0], g[e + 0], p0);
      p1 = fmaf(g[e + 1], g[e + 1], p1);
      p2 = fmaf(g[e + 2], g[e + 2], p2);
      p3 = fmaf(g[e + 3], g[e + 3], p3);
    }
    const float pp = (p0 + p1) + (p2 + p3);
    const float op = __shfl_xor(pp, 32);
    nx = h ? (op + pp) : (pp + op);
  }
  const float lv = 0.5f * __logf(fmaxf(nx, 1.4210855e-10f));
  const float sc = (nx > 1e-32f) ? (lv * __builtin_amdgcn_rcpf(nx)) : 0.f;

  __syncthreads();                     // done with sA as A; reuse for G^T
  // store G TRANSPOSED: sA[col][row] = G[row][col]  (so G[j][e] = sA[e][j])
  #pragma unroll
  for (int i = 0; i < 16; ++i) sA[c][16 * h + i] = g[i];
  if (h == 0) sSc[c] = sc;
  __syncthreads();

  // out[r][j] = sum_e sc_e * G[r][e] * G[j][e];  lane does row r=c, cols [16h,16h+16)
  float a[32];
  #pragma unroll
  for (int e = 0; e < 32; ++e) a[e] = sSc[e] * sA[e][c];   // sc_e * G[c][e]

  float* ob = eigTmp + ((size_t)blk * 1024 + c * 32 + 16 * h);
  #pragma unroll
  for (int q = 0; q < 4; ++q) {
    float4 acc = make_float4(0.f, 0.f, 0.f, 0.f);
    #pragma unroll
    for (int e = 0; e < 32; ++e) {
      const float4 gv = *(const float4*)&sA[e][16 * h + 4 * q];   // G[j..j+3][e], broadcast
      acc.x = fmaf(a[e], gv.x, acc.x);
      acc.y = fmaf(a[e], gv.y, acc.y);
      acc.z = fmaf(a[e], gv.z, acc.z);
      acc.w = fmaf(a[e], gv.w, acc.w);
    }
    *(float4*)(ob + 4 * q) = acc;
  }
}

// ---------------- K4: transpose (b,t,k,ij) -> out (b,k,ij,t) ----------------
__global__ __launch_bounds__(256) void k_tr(const float* __restrict__ eigTmp,
                                            float* __restrict__ out) {
  const int bk    = blockIdx.x >> 3;   // b*6 + k
  const int chunk = blockIdx.x & 7;
  const int b = bk / 6, k = bk % 6;
  const int ij0 = chunk * 128;
  const int tid = threadIdx.x;

  __shared__ float tile[128 * 59];

  for (int u = tid; u < 128 * NWIN; u += 256) {
    const int t = u >> 7, ijl = u & 127;
    tile[ijl * 59 + t] = eigTmp[((size_t)(b * NWIN + t) * 6 + k) * 1024 + ij0 + ijl];
  }
  __syncthreads();

  float* ob = out + ((size_t)bk * 1024 + ij0) * NWIN;
  for (int u = tid; u < 128 * NWIN; u += 256) {
    ob[u] = tile[(u / NWIN) * 59 + (u % NWIN)];
  }
}

extern "C" void kernel_launch(void* const* d_in, const int* in_sizes, int n_in,
                              void* d_out, int out_size, void* d_ws, size_t ws_size,
                              hipStream_t stream) {
  const float* x = (const float*)d_in[0];
  float* outp = (float*)d_out;

  const size_t SPEC_B = (size_t)8 * NFRM * NBIN * NC * sizeof(float2);   // 64.75 MB
  const size_t BAND_B = (size_t)NMAT * 1024 * sizeof(float);             // 11.4 MB

  float2* spec   = (float2*)d_ws;
  float*  part   = (float*)((char*)d_ws + SPEC_B);
  float*  eigTmp = (float*)d_ws;       // reuses spec region (dead after k_csd)

  int P = 1;
  if (ws_size >= SPEC_B + 2 * BAND_B) P = 2;   // P=4 regressed (R11): epilogue x2 > balance gain

  k_stft<<<dim3(8 * 32 * NFRM), dim3(128), 0, stream>>>(x, spec);
  k_csd <<<dim3(8 * NWIN, P),   dim3(256), 0, stream>>>(spec, part, P);
  k_eig <<<dim3(NMAT),          dim3(64),  0, stream>>>(part, eigTmp, P);
  k_tr  <<<dim3(48 * 8),        dim3(256), 0, stream>>>(eigTmp, outp);
}